// Round 5
// baseline (120.134 us; speedup 1.0000x reference)
//
#include <hip/hip_runtime.h>

// loss = 2*0.5 * dot(colsum(a), colsum(b)), a,b: (16384, 512) fp32.
// Memory-bound: 67 MB read -> ~11 us floor at 6.3 TB/s achievable.
// dur_us includes ~85-90 us of harness reset (256 MiB ws poison + input
// restore) — fixed. R5: single fused dispatch; blocks 0-31 double as
// reducers via release/acquire flags (poll for ==1, a value only we write;
// no dependence on the 0xAA poison).

#define ROWS  16384
#define COLS  512
#define NBLK  512                   // writer blocks == partial rows
#define NTHR  256
#define NT    (NBLK * NTHR)         // 131,072 float4 stride -> 16 iters/thread
#define NRED  32                    // reducer blocks (16 cols each)

typedef float vfloat4 __attribute__((ext_vector_type(4)));

__device__ __forceinline__ vfloat4 ntload(const vfloat4* p) {
    return __builtin_nontemporal_load(p);
}

// ws layout: pa[512][512] f32 (1 MB), pb[512][512] f32 (1 MB), flags[512] int.

__global__ __launch_bounds__(NTHR) void fused_colsum_dot(
        const vfloat4* __restrict__ a, const vfloat4* __restrict__ b,
        vfloat4* __restrict__ pa4, vfloat4* __restrict__ pb4,
        int* __restrict__ flags, float* __restrict__ out) {
    const int blk = blockIdx.x;
    const int tid = threadIdx.x;

    // out[0] := 0 at the coherent point, ordered before flags[0]=1 below,
    // which every reducer waits on before its atomicAdd.
    if (blk == 0 && tid == 0) atomicExch(out, 0.0f);

    // ---- phase 1: streaming column partials ----
    const int g0 = blk * NTHR + tid;
    vfloat4 sa = (vfloat4)(0.f);
    vfloat4 sb = (vfloat4)(0.f);
#pragma unroll
    for (int i = 0; i < 16; ++i) {
        sa += ntload(a + g0 + i * NT);
        sb += ntload(b + g0 + i * NT);
    }

    // fold 256 -> 128 threads (t and t+128 share a 4-col group)
    __shared__ vfloat4 la[128];
    __shared__ vfloat4 lb[128];
    if (tid >= 128) { la[tid - 128] = sa; lb[tid - 128] = sb; }
    __syncthreads();
    if (tid < 128) {
        sa += la[tid];
        sb += lb[tid];
        pa4[blk * 128 + tid] = sa;      // coalesced 16 B stores
        pb4[blk * 128 + tid] = sb;
    }
    // barrier drains vmcnt -> all partial stores complete before flag
    __syncthreads();
    if (tid == 0) {
        __hip_atomic_store(&flags[blk], 1, __ATOMIC_RELEASE,
                           __HIP_MEMORY_SCOPE_AGENT);
    }

    // ---- phase 2: blocks 0..31 reduce ----
    if (blk >= NRED) return;

    for (int i = tid; i < NBLK; i += NTHR) {
        while (__hip_atomic_load(&flags[i], __ATOMIC_ACQUIRE,
                                 __HIP_MEMORY_SCOPE_AGENT) != 1) {
            __builtin_amdgcn_s_sleep(2);
        }
    }
    __syncthreads();

    const float* pa = (const float*)pa4;
    const float* pb = (const float*)pb4;
    const int col = blk * 16 + (tid & 15);
    const int rc  = tid >> 4;           // 16 row-classes over 512 rows

    float va = 0.f, vb = 0.f;
#pragma unroll 8
    for (int r = rc; r < NBLK; r += 16) {
        va += pa[r * COLS + col];
        vb += pb[r * COLS + col];
    }
    // wave w holds row-classes 4w..4w+3: fold lanes l, l^16, l^32
    va += __shfl_xor(va, 16, 64); va += __shfl_xor(va, 32, 64);
    vb += __shfl_xor(vb, 16, 64); vb += __shfl_xor(vb, 32, 64);

    __shared__ float fa[4][16];
    __shared__ float fb[4][16];
    const int wave = tid >> 6, lane = tid & 63;
    if (lane < 16) { fa[wave][lane] = va; fb[wave][lane] = vb; }
    __syncthreads();
    if (tid < 16) {
        float ca = fa[0][tid] + fa[1][tid] + fa[2][tid] + fa[3][tid];
        float cb = fb[0][tid] + fb[1][tid] + fb[2][tid] + fb[3][tid];
        float p  = ca * cb;             // per-column product
        p += __shfl_xor(p, 1, 64);
        p += __shfl_xor(p, 2, 64);
        p += __shfl_xor(p, 4, 64);
        p += __shfl_xor(p, 8, 64);
        if (tid == 0) atomicAdd(out, p);    // 2*lambd = 1.0
    }
}

extern "C" void kernel_launch(void* const* d_in, const int* in_sizes, int n_in,
                              void* d_out, int out_size, void* d_ws, size_t ws_size,
                              hipStream_t stream) {
    const vfloat4* a = (const vfloat4*)d_in[0];
    const vfloat4* b = (const vfloat4*)d_in[1];
    float* out = (float*)d_out;

    vfloat4* pa4  = (vfloat4*)d_ws;                  // [512][128] vfloat4
    vfloat4* pb4  = pa4 + NBLK * (COLS / 4);         // [512][128] vfloat4
    int*     flgs = (int*)(pb4 + NBLK * (COLS / 4)); // [512] int

    fused_colsum_dot<<<NBLK, NTHR, 0, stream>>>(a, b, pa4, pb4, flgs, out);
}

// Round 6
// 94.479 us; speedup vs baseline: 1.2715x; 1.2715x over previous
//
#include <hip/hip_runtime.h>

// loss = 2*0.5 * dot(colsum(a), colsum(b)), a,b: (16384, 512) fp32.
// Memory-bound. dur_us includes ~65-90 us of harness reset (256 MiB ws
// poison fill ~42 us + 134 MB input restore ~21 us + gaps) — fixed cost.
// R6 = R4 (best, 100.5 us) with ONE change: plain loads instead of
// nontemporal. The harness input-restore leaves ~32 MB in L2 and the rest
// in the 256 MiB Infinity Cache; plain loads can hit those (L2 ~34 TB/s).
// R5's single-dispatch fusion with release/acquire flags REGRESSED
// (41 us kernel: 512 wbl2 releases + 8K spinning acquire loads trash L2)
// — dispatch-boundary coherence of the 2-kernel split is free and faster.

#define ROWS  16384
#define COLS  512
#define PB    512                   // stage-1 blocks == partial rows
#define NTHR  256
#define NT    (PB * NTHR)           // 131,072 float4 stride -> 16 iters/thread

typedef float vfloat4 __attribute__((ext_vector_type(4)));

// ws: pa[512][512] floats (1 MB), pb[512][512] floats (1 MB)

__global__ __launch_bounds__(NTHR) void colsum_partial(
        const vfloat4* __restrict__ a, const vfloat4* __restrict__ b,
        vfloat4* __restrict__ pa, vfloat4* __restrict__ pb,
        float* __restrict__ out) {
    const int tid = threadIdx.x;
    const int g0  = blockIdx.x * NTHR + tid;

    if (blockIdx.x == 0 && tid == 0) out[0] = 0.0f;  // for stage-2 atomics

    vfloat4 sa = (vfloat4)(0.f);
    vfloat4 sb = (vfloat4)(0.f);

    // stride NT is a multiple of 128 -> each thread's 4-column group is fixed
#pragma unroll
    for (int i = 0; i < 16; ++i) {
        sa += a[g0 + i * NT];
        sb += b[g0 + i * NT];
    }

    // threads t and t+128 hold the same 4-column group -> fold 256->128
    __shared__ vfloat4 la[128];
    __shared__ vfloat4 lb[128];
    if (tid >= 128) { la[tid - 128] = sa; lb[tid - 128] = sb; }
    __syncthreads();
    if (tid < 128) {
        sa += la[tid];
        sb += lb[tid];
        pa[blockIdx.x * 128 + tid] = sa;   // coalesced 16B store
        pb[blockIdx.x * 128 + tid] = sb;
    }
}

// 32 blocks x 256 threads; block b owns cols 16b..16b+15.
// thread t: col = 16b + (t&15), row-class rc = t>>4 (16 classes over PB rows).
__global__ __launch_bounds__(NTHR) void reduce_dot(
        const float* __restrict__ pa, const float* __restrict__ pb,
        float* __restrict__ out) {
    const int t   = threadIdx.x;
    const int col = blockIdx.x * 16 + (t & 15);
    const int rc  = t >> 4;

    float va = 0.f, vb = 0.f;
#pragma unroll 8
    for (int r = rc; r < PB; r += 16) {
        va += pa[r * COLS + col];
        vb += pb[r * COLS + col];
    }
    // wave w covers row-classes 4w..4w+3; fold them (lanes l, l^16, l^32)
    va += __shfl_xor(va, 16, 64); va += __shfl_xor(va, 32, 64);
    vb += __shfl_xor(vb, 16, 64); vb += __shfl_xor(vb, 32, 64);

    __shared__ float sa4[4][16];
    __shared__ float sb4[4][16];
    const int wave = t >> 6, lane = t & 63;
    if (lane < 16) { sa4[wave][lane] = va; sb4[wave][lane] = vb; }
    __syncthreads();
    if (t < 16) {
        float ca = sa4[0][t] + sa4[1][t] + sa4[2][t] + sa4[3][t];
        float cb = sb4[0][t] + sb4[1][t] + sb4[2][t] + sb4[3][t];
        float p  = ca * cb;                     // per-column product
        p += __shfl_xor(p, 1, 64);
        p += __shfl_xor(p, 2, 64);
        p += __shfl_xor(p, 4, 64);
        p += __shfl_xor(p, 8, 64);
        if (t == 0) atomicAdd(out, p);          // 2*lambd = 1.0
    }
}

extern "C" void kernel_launch(void* const* d_in, const int* in_sizes, int n_in,
                              void* d_out, int out_size, void* d_ws, size_t ws_size,
                              hipStream_t stream) {
    const vfloat4* a = (const vfloat4*)d_in[0];
    const vfloat4* b = (const vfloat4*)d_in[1];
    float* out = (float*)d_out;

    vfloat4* pa = (vfloat4*)d_ws;               // [512][128] vfloat4
    vfloat4* pb = pa + PB * (COLS / 4);         // [512][128] vfloat4

    colsum_partial<<<PB, NTHR, 0, stream>>>(a, b, pa, pb, out);
    reduce_dot<<<COLS / 16, NTHR, 0, stream>>>((const float*)pa, (const float*)pb, out);
}